// Round 7
// baseline (474.915 us; speedup 1.0000x reference)
//
#include <hip/hip_runtime.h>
#include <hip/hip_bf16.h>

#define DEVFN __device__ __forceinline__

typedef __attribute__((ext_vector_type(4))) float f32x4;
typedef __attribute__((ext_vector_type(8))) short s16x8;
typedef __attribute__((ext_vector_type(2))) short s16x2;
typedef __attribute__((ext_vector_type(8))) __bf16 bf16x8;

union FragU { s16x8 s; bf16x8 b; };

DEVFN short f2bs(float x) {
  union { __hip_bfloat16 h; short s; } u;
  u.h = __float2bfloat16(x);
  return u.s;
}

DEVFN void gload16(const void* g, void* l) {
  __builtin_amdgcn_global_load_lds(
      (const __attribute__((address_space(1))) void*)g,
      (__attribute__((address_space(3))) void*)l, 16, 0, 0);
}

template <int N> DEVFN void waitcnt_vm() {
  if constexpr (N == 0) asm volatile("s_waitcnt vmcnt(0)" ::: "memory");
  else if constexpr (N == 4) asm volatile("s_waitcnt vmcnt(4)" ::: "memory");
  else if constexpr (N == 6) asm volatile("s_waitcnt vmcnt(6)" ::: "memory");
  else if constexpr (N == 8) asm volatile("s_waitcnt vmcnt(8)" ::: "memory");
  else static_assert(N == 0, "unsupported vmcnt");
}

// in: [Z][C][L] f32 -> out: [Z][L][C] bf16. Block (32,8): C-tile 64, L-tile 32.
__global__ __launch_bounds__(256) void transpose_cvt(
    const float* __restrict__ in, short* __restrict__ out, int C, int L) {
  __shared__ float tile[64][33];
  const int l0 = blockIdx.x * 32, c0 = blockIdx.y * 64;
  const size_t base = (size_t)blockIdx.z * C * L;
  const int tx = threadIdx.x, ty = threadIdx.y;
#pragma unroll
  for (int i = ty; i < 64; i += 8)
    tile[i][tx] = in[base + (size_t)(c0 + i) * L + l0 + tx];
  __syncthreads();
#pragma unroll
  for (int i = ty; i < 32; i += 8) {
    s16x2 v;
    v[0] = f2bs(tile[2 * tx][i]);
    v[1] = f2bs(tile[2 * tx + 1][i]);
    *(s16x2*)&out[base + (size_t)(l0 + i) * C + c0 + 2 * tx] = v;
  }
}

// All six weight transposes + both bias concats, one launch.
__global__ __launch_bounds__(256) void prep_weights(
    const float* __restrict__ Wq1, const float* __restrict__ Wk1,
    const float* __restrict__ Wv1, const float* __restrict__ Wq2,
    const float* __restrict__ Wk2, const float* __restrict__ Wv2,
    short* wq1t, short* wk1t, short* wv1t,
    short* wq2t, short* wk2t, short* wv2t,
    const float* __restrict__ bq1, const float* __restrict__ bk1,
    const float* __restrict__ bq2, const float* __restrict__ bk2,
    float* b1c, float* b2c) {
  const int z = blockIdx.z;
  if (z == 6) {
    if (blockIdx.y != 0 || blockIdx.x >= 8) return;
    const int bx = blockIdx.x;
    const int tid = threadIdx.y * 32 + threadIdx.x;
    const int i = (bx & 3) * 256 + tid;
    const float* s = (bx < 4) ? ((i < 512) ? bq1 : bk1)
                              : ((i < 512) ? bq2 : bk2);
    float* d = (bx < 4) ? b1c : b2c;
    d[i] = s[i & 511];
    return;
  }
  const float* W; short* O; int C;
  switch (z) {
    case 0: W = Wq1; O = wq1t; C = 512; break;
    case 1: W = Wk1; O = wk1t; C = 512; break;
    case 2: W = Wv1; O = wv1t; C = 512; break;
    case 3: W = Wq2; O = wq2t; C = 768; break;
    case 4: W = Wk2; O = wk2t; C = 768; break;
    default: W = Wv2; O = wv2t; C = 768; break;
  }
  if (blockIdx.y * 64 >= (unsigned)C) return;
  const int L = 512;
  __shared__ float tile[64][33];
  const int l0 = blockIdx.x * 32, c0 = blockIdx.y * 64;
  const int tx = threadIdx.x, ty = threadIdx.y;
#pragma unroll
  for (int i = ty; i < 64; i += 8)
    tile[i][tx] = W[(size_t)(c0 + i) * L + l0 + tx];
  __syncthreads();
#pragma unroll
  for (int i = ty; i < 32; i += 8) {
    s16x2 v;
    v[0] = f2bs(tile[2 * tx][i]);
    v[1] = f2bs(tile[2 * tx + 1][i]);
    *(s16x2*)&O[(size_t)(l0 + i) * C + c0 + 2 * tx] = v;
  }
}

// ---------------------------------------------------------------------------
// 2-blocks/CU pipelined GEMM: C[m][n] = sum_k A[m][k]*Bt[n][k] (+bias).
// 256 threads = 4 waves (2M x 2N). Tile BM x 128, BM = MW*32 (MW=8 or 4).
// Per-wave (MW*16) x 64 output = acc[MW][4]; 32 (or 16) MFMA per BK=32 step.
// 3 LDS buffers of (BM+128)*64 B (72 KiB @ MW=8) + VGPR<=256 => 2 blocks/CU:
// cross-block TLP fills barrier/vmcnt drains (m114 mechanism).
// Depth-2 prefetch, steady vmcnt(LPT), one barrier per K-step.
// XCD remap (T1): h -> (h%8)*(NB/8)+h/8 when NB%8==0 (all call sites).
// LDS layout: byte(r,cb) = (r>>1)*128 + (r&1)*64 + (cb ^ (((r>>1)&3)<<4)),
// linear gload dest + inverse-permuted global source (rule 21).
// OUTMODE: 0=bf16, 1=f32, 2=sigmoid f32, 3=sigmoid f32 + bf16 to C2p
// BIASMODE: 0 none, 1 per-n, 2 per-m.  Requires NT=K/32 >= 2.
// ---------------------------------------------------------------------------
template <int OUTMODE, int BIASMODE, int MW>
__global__ __launch_bounds__(256, 2) void gemm4(
    const short* __restrict__ Ap, const short* __restrict__ Btp,
    const float* __restrict__ bias, void* __restrict__ Cptr,
    short* __restrict__ C2p,
    int K, int lda, int ldb, int ldc,
    long long sA, long long sB, long long sC, float scale) {
  constexpr int BM = MW * 32;
  constexpr int LA = BM / 64;         // A gloads/thread (4096B chunks)
  constexpr int LB = 2;               // B gloads/thread
  constexpr int LPT = LA + LB;
  constexpr int ABYTES = BM * 64;
  constexpr int BUFB = (BM + 128) * 64;
  __shared__ __align__(16) char smem[3 * BUFB];
  const int tid = threadIdx.x;
  const int lane = tid & 63, wid = tid >> 6;
  const int wm = wid >> 1, wn = wid & 1;

  // ---- XCD-aware bijective block remap (T1) ----
  const unsigned gx = gridDim.x, gy = gridDim.y, gz = gridDim.z;
  const unsigned NB = gx * gy * gz;
  unsigned h = blockIdx.x + gx * (blockIdx.y + gy * blockIdx.z);
  unsigned l = ((NB & 7u) == 0u) ? (h & 7u) * (NB >> 3) + (h >> 3) : h;
  const unsigned bx = l % gx;
  const unsigned rem = l / gx;
  const unsigned by = rem % gy;
  const unsigned bz = rem / gy;

  const int zb = bz;
  const int m0 = by * BM, n0 = bx * 128;
  const char* Ab = (const char*)(Ap + (size_t)zb * sA);
  const char* Bb = (const char*)(Btp + (size_t)zb * sB);
  const size_t lda2 = (size_t)lda * 2, ldb2 = (size_t)ldb * 2;

  // Staging: dest d = j*4096 + tid*16 (linear). Inverse-map to (row, colbyte).
  int s_r[LA], s_cb[LA];
#pragma unroll
  for (int j = 0; j < LA; ++j) {
    const int d = j * 4096 + tid * 16;
    const int line = d >> 7;
    s_r[j] = line * 2 + ((d >> 6) & 1);
    s_cb[j] = (d & 63) ^ ((line & 3) << 4);
  }

  f32x4 acc[MW][4] = {};
  const int frow = lane & 15, fkg = lane >> 4;

  int ra[MW], rb[4];
#pragma unroll
  for (int mf = 0; mf < MW; ++mf) {
    const int R = wm * (MW * 16) + mf * 16 + frow;
    ra[mf] = (R >> 1) * 128 + (R & 1) * 64 + ((fkg * 16) ^ (((R >> 1) & 3) << 4));
  }
#pragma unroll
  for (int nf = 0; nf < 4; ++nf) {
    const int R = wn * 64 + nf * 16 + frow;
    rb[nf] = (R >> 1) * 128 + (R & 1) * 64 + ((fkg * 16) ^ (((R >> 1) & 3) << 4));
  }

  const int NT = K >> 5;

#define STAGE(t)                                                         \
  {                                                                      \
    char* base_ = smem + ((t) % 3) * BUFB;                               \
    const size_t kb_ = (size_t)(t) * 64;                                 \
    _Pragma("unroll")                                                    \
    for (int j = 0; j < LA; ++j)                                         \
      gload16(Ab + (size_t)(m0 + s_r[j]) * lda2 + kb_ + s_cb[j],         \
              base_ + j * 4096 + tid * 16);                              \
    _Pragma("unroll")                                                    \
    for (int j = 0; j < LB; ++j)                                         \
      gload16(Bb + (size_t)(n0 + s_r[j]) * ldb2 + kb_ + s_cb[j],         \
              base_ + ABYTES + j * 4096 + tid * 16);                     \
  }

  // prologue: 2 tiles in flight, wait for tile 0 (NT >= 2 at all call sites)
  STAGE(0);
  STAGE(1);
  waitcnt_vm<LPT>();
  __builtin_amdgcn_sched_barrier(0);
  __builtin_amdgcn_s_barrier();
  __builtin_amdgcn_sched_barrier(0);

  for (int t = 0; t < NT; ++t) {
    if (t + 2 < NT) STAGE(t + 2);
    const char* la = smem + (t % 3) * BUFB;
    const char* lb = la + ABYTES;
    FragU fa[MW], fb[4];
#pragma unroll
    for (int mf = 0; mf < MW; ++mf) fa[mf].s = *(const s16x8*)(la + ra[mf]);
#pragma unroll
    for (int nf = 0; nf < 4; ++nf) fb[nf].s = *(const s16x8*)(lb + rb[nf]);
    asm volatile("s_waitcnt lgkmcnt(0)" ::: "memory");
    __builtin_amdgcn_sched_barrier(0);
    __builtin_amdgcn_s_setprio(1);
#pragma unroll
    for (int mf = 0; mf < MW; ++mf)
#pragma unroll
      for (int nf = 0; nf < 4; ++nf)
        acc[mf][nf] = __builtin_amdgcn_mfma_f32_16x16x32_bf16(
            fa[mf].b, fb[nf].b, acc[mf][nf], 0, 0, 0);
    __builtin_amdgcn_s_setprio(0);
    if (t + 2 < NT) {
      waitcnt_vm<LPT>();
    } else if (t + 1 < NT) {
      waitcnt_vm<0>();
    } else {
      break;  // last iteration: no further LDS reads
    }
    __builtin_amdgcn_sched_barrier(0);
    __builtin_amdgcn_s_barrier();
    __builtin_amdgcn_sched_barrier(0);
  }
#undef STAGE

  const int rbase = (lane >> 4) * 4, cbase = lane & 15;
#pragma unroll
  for (int mf = 0; mf < MW; ++mf) {
#pragma unroll
    for (int nf = 0; nf < 4; ++nf) {
      const int gcol = n0 + wn * 64 + nf * 16 + cbase;
      float bn = (BIASMODE == 1) ? bias[gcol] : 0.f;
#pragma unroll
      for (int r = 0; r < 4; ++r) {
        const int grow = m0 + wm * (MW * 16) + mf * 16 + rbase + r;
        const size_t idx = (size_t)zb * sC + (size_t)grow * ldc + gcol;
        float v = acc[mf][nf][r];
        if constexpr (BIASMODE == 2) v += bias[grow]; else v += bn;
        if constexpr (OUTMODE == 0) {
          ((short*)Cptr)[idx] = f2bs(v);
        } else if constexpr (OUTMODE == 1) {
          ((float*)Cptr)[idx] = v;
        } else if constexpr (OUTMODE == 2) {
          ((float*)Cptr)[idx] = 1.0f / (1.0f + __expf(-v * scale));
        } else {
          float p = 1.0f / (1.0f + __expf(-v * scale));
          ((float*)Cptr)[idx] = p;
          C2p[idx] = f2bs(p);
        }
      }
    }
  }
}

// ---------------------------------------------------------------------------
// Fallback (tierB only): gload-staged 128x128 BK=64 GEMM, AF32 supported.
// ---------------------------------------------------------------------------
template <int OUTMODE, int BIASMODE, int AF32>
__global__ __launch_bounds__(256) void gemm_bt(
    const void* __restrict__ Aptr, const short* __restrict__ Btp,
    const float* __restrict__ bias, void* __restrict__ Cptr,
    short* __restrict__ C2p,
    int K, int lda, int ldb, int ldc,
    long long sA, long long sB, long long sC, float scale) {
  __shared__ __align__(16) short lsA[128 * 64];
  __shared__ __align__(16) short lsB[128 * 64];
  const int tid = threadIdx.x;
  const int lane = tid & 63, wid = tid >> 6;
  const int zb = blockIdx.z;
  const int m0 = blockIdx.y * 128, n0 = blockIdx.x * 128;
  const short* Ab = AF32 ? nullptr : (const short*)Aptr + (size_t)zb * sA;
  const float* Af = AF32 ? (const float*)Aptr + (size_t)zb * sA : nullptr;
  const short* Bt = Btp + (size_t)zb * sB;

  f32x4 acc[4][4] = {};
  const int woffM = (wid >> 1) * 64, woffN = (wid & 1) * 64;
  const int frow = lane & 15, fkg = lane >> 4;

  for (int k0 = 0; k0 < K; k0 += 64) {
    if (k0) __syncthreads();
    if constexpr (!AF32) {
#pragma unroll
      for (int i = 0; i < 4; ++i) {
        const int f = i * 4096 + tid * 16;
        const int row = f >> 7, colb = f & 127;
        gload16((const char*)Ab + ((size_t)(m0 + row) * lda + k0) * 2 + colb,
                (char*)lsA + f);
      }
    } else {
#pragma unroll
      for (int i = 0; i < 8; ++i) {
        int f = tid + i * 256;
        int row = f >> 4, c4 = f & 15;
        f32x4 v = *(const f32x4*)&Af[(size_t)(m0 + row) * lda + k0 + c4 * 4];
        union { short s[4]; unsigned long long q; } cv;
#pragma unroll
        for (int j = 0; j < 4; ++j) cv.s[j] = f2bs(v[j]);
        *(unsigned long long*)&lsA[row * 64 + c4 * 4] = cv.q;
      }
    }
#pragma unroll
    for (int i = 0; i < 4; ++i) {
      const int f = i * 4096 + tid * 16;
      const int row = f >> 7, colb = f & 127;
      gload16((const char*)Bt + ((size_t)(n0 + row) * ldb + k0) * 2 + colb,
              (char*)lsB + f);
    }
    __syncthreads();
#pragma unroll
    for (int kk = 0; kk < 2; ++kk) {
      const int kb = kk * 32 + fkg * 8;
      FragU fa[4], fb[4];
#pragma unroll
      for (int mf = 0; mf < 4; ++mf)
        fa[mf].s = *(const s16x8*)&lsA[(woffM + mf * 16 + frow) * 64 + kb];
#pragma unroll
      for (int nf = 0; nf < 4; ++nf)
        fb[nf].s = *(const s16x8*)&lsB[(woffN + nf * 16 + frow) * 64 + kb];
#pragma unroll
      for (int mf = 0; mf < 4; ++mf)
#pragma unroll
        for (int nf = 0; nf < 4; ++nf)
          acc[mf][nf] = __builtin_amdgcn_mfma_f32_16x16x32_bf16(
              fa[mf].b, fb[nf].b, acc[mf][nf], 0, 0, 0);
    }
  }

  const int rbase = (lane >> 4) * 4, cbase = lane & 15;
#pragma unroll
  for (int mf = 0; mf < 4; ++mf) {
#pragma unroll
    for (int nf = 0; nf < 4; ++nf) {
      const int gcol = n0 + woffN + nf * 16 + cbase;
      float bn = (BIASMODE == 1) ? bias[gcol] : 0.f;
#pragma unroll
      for (int r = 0; r < 4; ++r) {
        const int grow = m0 + woffM + mf * 16 + rbase + r;
        const size_t idx = (size_t)zb * sC + (size_t)grow * ldc + gcol;
        float v = acc[mf][nf][r];
        if constexpr (BIASMODE == 2) v += bias[grow]; else v += bn;
        if constexpr (OUTMODE == 0) {
          ((short*)Cptr)[idx] = f2bs(v);
        } else if constexpr (OUTMODE == 1) {
          ((float*)Cptr)[idx] = v;
        } else if constexpr (OUTMODE == 2) {
          ((float*)Cptr)[idx] = 1.0f / (1.0f + __expf(-v * scale));
        } else {
          float p = 1.0f / (1.0f + __expf(-v * scale));
          ((float*)Cptr)[idx] = p;
          C2p[idx] = f2bs(p);
        }
      }
    }
  }
}

extern "C" void kernel_launch(void* const* d_in, const int* in_sizes, int n_in,
                              void* d_out, int out_size, void* d_ws, size_t ws_size,
                              hipStream_t stream) {
  const float* in1 = (const float*)d_in[0];   // [16][512][2048]
  const float* in2 = (const float*)d_in[1];   // [16][768][1024]
  const float* Wq1 = (const float*)d_in[2];  const float* bq1 = (const float*)d_in[3];
  const float* Wk1 = (const float*)d_in[4];  const float* bk1 = (const float*)d_in[5];
  const float* Wv1 = (const float*)d_in[6];  const float* bv1 = (const float*)d_in[7];
  const float* Wq2 = (const float*)d_in[8];  const float* bq2 = (const float*)d_in[9];
  const float* Wk2 = (const float*)d_in[10]; const float* bk2 = (const float*)d_in[11];
  const float* Wv2 = (const float*)d_in[12]; const float* bv2 = (const float*)d_in[13];

  float* out = (float*)d_out;
  float* ctx2   = out;                                      // [16][2048][512]
  float* probs2 = out + (size_t)16 * 2048 * 512;            // [16][2048][1024]
  float* ctx1   = probs2 + (size_t)16 * 2048 * 1024;        // [16][1024][512]
  float* probs1 = ctx1 + (size_t)16 * 1024 * 512;           // [16][1024][2048]

  char* ws = (char*)d_ws;
  constexpr size_t O_WQ1T = 0;
  constexpr size_t O_WK1T = O_WQ1T + (size_t)512 * 512 * 2;
  constexpr size_t O_WV1T = O_WK1T + (size_t)512 * 512 * 2;
  constexpr size_t O_WQ2T = O_WV1T + (size_t)512 * 512 * 2;
  constexpr size_t O_WK2T = O_WQ2T + (size_t)768 * 512 * 2;
  constexpr size_t O_WV2T = O_WK2T + (size_t)768 * 512 * 2;
  constexpr size_t O_B1   = O_WV2T + (size_t)768 * 512 * 2;
  constexpr size_t O_B2   = O_B1 + 4096;
  constexpr size_t O_QK1  = O_B2 + 4096;                          // [32768][1024]
  constexpr size_t O_V1T  = O_QK1 + (size_t)32768 * 1024 * 2;     // [16][512][2048]
  constexpr size_t O_QK2  = O_V1T + (size_t)16 * 512 * 2048 * 2;  // [16384][1024]
  constexpr size_t O_V2T  = O_QK2 + (size_t)16384 * 1024 * 2;     // [16][512][1024]
  constexpr size_t O_X1B  = O_V2T + (size_t)16 * 512 * 1024 * 2;  // [32768][512]
  constexpr size_t O_X2B  = O_X1B + (size_t)32768 * 512 * 2;      // [16384][768]
  constexpr size_t O_PB1  = O_X2B + (size_t)16384 * 768 * 2;      // bf16 probs1
  constexpr size_t O_PB2  = O_PB1 + (size_t)16 * 1024 * 2048 * 2; // bf16 probs2
  constexpr size_t NEED_A = O_PB2 + (size_t)16 * 2048 * 1024 * 2;
  constexpr size_t NEED_B = O_PB1;

  short* wq1t = (short*)(ws + O_WQ1T);
  short* wk1t = (short*)(ws + O_WK1T);
  short* wv1t = (short*)(ws + O_WV1T);
  short* wq2t = (short*)(ws + O_WQ2T);
  short* wk2t = (short*)(ws + O_WK2T);
  short* wv2t = (short*)(ws + O_WV2T);
  float* b1c  = (float*)(ws + O_B1);
  float* b2c  = (float*)(ws + O_B2);
  short* qk1  = (short*)(ws + O_QK1);
  short* v1t  = (short*)(ws + O_V1T);
  short* qk2  = (short*)(ws + O_QK2);
  short* v2t  = (short*)(ws + O_V2T);
  short* x1b  = (short*)(ws + O_X1B);
  short* x2b  = (short*)(ws + O_X2B);
  short* pb1  = (short*)(ws + O_PB1);
  short* pb2  = (short*)(ws + O_PB2);

  const bool tierA = ws_size >= NEED_A;
  const bool tierB = ws_size >= NEED_B;
  if (!tierB) { x1b = (short*)probs1; x2b = (short*)probs2; }

  dim3 blk256(256);
  dim3 blkT(32, 8);

  // ---- stage 0 ----
  transpose_cvt<<<dim3(64, 8, 16), blkT, 0, stream>>>(in1, x1b, 512, 2048);
  transpose_cvt<<<dim3(32, 12, 16), blkT, 0, stream>>>(in2, x2b, 768, 1024);
  prep_weights<<<dim3(16, 12, 7), blkT, 0, stream>>>(
      Wq1, Wk1, Wv1, Wq2, Wk2, Wv2, wq1t, wk1t, wv1t, wq2t, wk2t, wv2t,
      bq1, bk1, bq2, bk2, b1c, b2c);

  const float scale = 0.04419417382415922f;  // 1/sqrt(512)
  const short* q1p = qk1;        // lda 1024
  const short* k1p = qk1 + 512;
  const short* q2p = qk2;
  const short* k2p = qk2 + 512;

  if (tierA) {
    // ---- stage 1: projections ----
    gemm4<0, 1, 8><<<dim3(8, 128, 1), blk256, 0, stream>>>(
        x1b, wq1t, b1c, qk1, nullptr, 512, 512, 512, 1024, 0, 0, 0, 1.f);
    gemm4<0, 1, 8><<<dim3(8, 64, 1), blk256, 0, stream>>>(
        x2b, wq2t, b2c, qk2, nullptr, 768, 768, 768, 1024, 0, 0, 0, 1.f);
    gemm4<0, 2, 8><<<dim3(16, 2, 16), blk256, 0, stream>>>(
        wv1t, x1b, bv1, v1t, nullptr, 512, 512, 512, 2048,
        0, (long long)2048 * 512, (long long)512 * 2048, 1.f);
    gemm4<0, 2, 4><<<dim3(8, 4, 16), blk256, 0, stream>>>(
        wv2t, x2b, bv2, v2t, nullptr, 768, 768, 768, 1024,
        0, (long long)1024 * 768, (long long)512 * 1024, 1.f);
    // ---- stage 2: scores + sigmoid (dual store f32 + bf16) ----
    gemm4<3, 0, 8><<<dim3(16, 4, 16), blk256, 0, stream>>>(
        q2p, k1p, nullptr, probs1, pb1, 512, 1024, 1024, 2048,
        (long long)1024 * 1024, (long long)2048 * 1024, (long long)1024 * 2048, scale);
    gemm4<3, 0, 8><<<dim3(8, 8, 16), blk256, 0, stream>>>(
        q1p, k2p, nullptr, probs2, pb2, 512, 1024, 1024, 1024,
        (long long)2048 * 1024, (long long)1024 * 1024, (long long)2048 * 1024, scale);
    // ---- stage 3: ctx = probs(bf16) @ v^T ----
    gemm4<1, 0, 4><<<dim3(4, 8, 16), blk256, 0, stream>>>(
        pb1, v1t, nullptr, ctx1, nullptr, 2048, 2048, 2048, 512,
        (long long)1024 * 2048, (long long)512 * 2048, (long long)1024 * 512, 1.f);
    gemm4<1, 0, 8><<<dim3(4, 8, 16), blk256, 0, stream>>>(
        pb2, v2t, nullptr, ctx2, nullptr, 1024, 1024, 1024, 512,
        (long long)2048 * 1024, (long long)512 * 1024, (long long)2048 * 512, 1.f);
  } else {
    gemm_bt<0, 1, 0><<<dim3(8, 256, 1), blk256, 0, stream>>>(
        x1b, wq1t, b1c, qk1, nullptr, 512, 512, 512, 1024, 0, 0, 0, 1.f);
    gemm_bt<0, 1, 0><<<dim3(8, 128, 1), blk256, 0, stream>>>(
        x2b, wq2t, b2c, qk2, nullptr, 768, 768, 768, 1024, 0, 0, 0, 1.f);
    gemm_bt<0, 2, 0><<<dim3(16, 4, 16), blk256, 0, stream>>>(
        wv1t, x1b, bv1, v1t, nullptr, 512, 512, 512, 2048,
        0, (long long)2048 * 512, (long long)512 * 2048, 1.f);
    gemm_bt<0, 2, 0><<<dim3(8, 4, 16), blk256, 0, stream>>>(
        wv2t, x2b, bv2, v2t, nullptr, 768, 768, 768, 1024,
        0, (long long)1024 * 768, (long long)512 * 1024, 1.f);
    gemm_bt<2, 0, 0><<<dim3(16, 8, 16), blk256, 0, stream>>>(
        q2p, k1p, nullptr, probs1, nullptr, 512, 1024, 1024, 2048,
        (long long)1024 * 1024, (long long)2048 * 1024, (long long)1024 * 2048, scale);
    gemm_bt<2, 0, 0><<<dim3(8, 16, 16), blk256, 0, stream>>>(
        q1p, k2p, nullptr, probs2, nullptr, 512, 1024, 1024, 1024,
        (long long)2048 * 1024, (long long)1024 * 1024, (long long)2048 * 1024, scale);
    gemm_bt<1, 0, 1><<<dim3(4, 8, 16), blk256, 0, stream>>>(
        probs1, v1t, nullptr, ctx1, nullptr, 2048, 2048, 2048, 512,
        (long long)1024 * 2048, (long long)512 * 2048, (long long)1024 * 512, 1.f);
    gemm_bt<1, 0, 1><<<dim3(4, 16, 16), blk256, 0, stream>>>(
        probs2, v2t, nullptr, ctx2, nullptr, 1024, 1024, 1024, 512,
        (long long)2048 * 1024, (long long)512 * 1024, (long long)2048 * 512, 1.f);
  }
}

// Round 8
// 440.290 us; speedup vs baseline: 1.0786x; 1.0786x over previous
//
#include <hip/hip_runtime.h>
#include <hip/hip_bf16.h>

#define DEVFN __device__ __forceinline__

typedef __attribute__((ext_vector_type(4))) float f32x4;
typedef __attribute__((ext_vector_type(8))) short s16x8;
typedef __attribute__((ext_vector_type(2))) short s16x2;
typedef __attribute__((ext_vector_type(8))) __bf16 bf16x8;

union FragU { s16x8 s; bf16x8 b; };

DEVFN short f2bs(float x) {
  union { __hip_bfloat16 h; short s; } u;
  u.h = __float2bfloat16(x);
  return u.s;
}

DEVFN void gload16(const void* g, void* l) {
  __builtin_amdgcn_global_load_lds(
      (const __attribute__((address_space(1))) void*)g,
      (__attribute__((address_space(3))) void*)l, 16, 0, 0);
}

template <int N> DEVFN void waitcnt_vm() {
  if constexpr (N == 0) asm volatile("s_waitcnt vmcnt(0)" ::: "memory");
  else if constexpr (N == 3) asm volatile("s_waitcnt vmcnt(3)" ::: "memory");
  else if constexpr (N == 4) asm volatile("s_waitcnt vmcnt(4)" ::: "memory");
  else if constexpr (N == 6) asm volatile("s_waitcnt vmcnt(6)" ::: "memory");
  else if constexpr (N == 8) asm volatile("s_waitcnt vmcnt(8)" ::: "memory");
  else static_assert(N == 0, "unsupported vmcnt");
}

// in: [Z][C][L] f32 -> out: [Z][L][C] bf16. Block (32,8): C-tile 64, L-tile 32.
__global__ __launch_bounds__(256) void transpose_cvt(
    const float* __restrict__ in, short* __restrict__ out, int C, int L) {
  __shared__ float tile[64][33];
  const int l0 = blockIdx.x * 32, c0 = blockIdx.y * 64;
  const size_t base = (size_t)blockIdx.z * C * L;
  const int tx = threadIdx.x, ty = threadIdx.y;
#pragma unroll
  for (int i = ty; i < 64; i += 8)
    tile[i][tx] = in[base + (size_t)(c0 + i) * L + l0 + tx];
  __syncthreads();
#pragma unroll
  for (int i = ty; i < 32; i += 8) {
    s16x2 v;
    v[0] = f2bs(tile[2 * tx][i]);
    v[1] = f2bs(tile[2 * tx + 1][i]);
    *(s16x2*)&out[base + (size_t)(l0 + i) * C + c0 + 2 * tx] = v;
  }
}

// All six weight transposes + both bias concats, one launch.
__global__ __launch_bounds__(256) void prep_weights(
    const float* __restrict__ Wq1, const float* __restrict__ Wk1,
    const float* __restrict__ Wv1, const float* __restrict__ Wq2,
    const float* __restrict__ Wk2, const float* __restrict__ Wv2,
    short* wq1t, short* wk1t, short* wv1t,
    short* wq2t, short* wk2t, short* wv2t,
    const float* __restrict__ bq1, const float* __restrict__ bk1,
    const float* __restrict__ bq2, const float* __restrict__ bk2,
    float* b1c, float* b2c) {
  const int z = blockIdx.z;
  if (z == 6) {
    if (blockIdx.y != 0 || blockIdx.x >= 8) return;
    const int bx = blockIdx.x;
    const int tid = threadIdx.y * 32 + threadIdx.x;
    const int i = (bx & 3) * 256 + tid;
    const float* s = (bx < 4) ? ((i < 512) ? bq1 : bk1)
                              : ((i < 512) ? bq2 : bk2);
    float* d = (bx < 4) ? b1c : b2c;
    d[i] = s[i & 511];
    return;
  }
  const float* W; short* O; int C;
  switch (z) {
    case 0: W = Wq1; O = wq1t; C = 512; break;
    case 1: W = Wk1; O = wk1t; C = 512; break;
    case 2: W = Wv1; O = wv1t; C = 512; break;
    case 3: W = Wq2; O = wq2t; C = 768; break;
    case 4: W = Wk2; O = wk2t; C = 768; break;
    default: W = Wv2; O = wv2t; C = 768; break;
  }
  if (blockIdx.y * 64 >= (unsigned)C) return;
  const int L = 512;
  __shared__ float tile[64][33];
  const int l0 = blockIdx.x * 32, c0 = blockIdx.y * 64;
  const int tx = threadIdx.x, ty = threadIdx.y;
#pragma unroll
  for (int i = ty; i < 64; i += 8)
    tile[i][tx] = W[(size_t)(c0 + i) * L + l0 + tx];
  __syncthreads();
#pragma unroll
  for (int i = ty; i < 32; i += 8) {
    s16x2 v;
    v[0] = f2bs(tile[2 * tx][i]);
    v[1] = f2bs(tile[2 * tx + 1][i]);
    *(s16x2*)&O[(size_t)(l0 + i) * C + c0 + 2 * tx] = v;
  }
}

// ---------------------------------------------------------------------------
// Dual-GEMM launch (two independent GEMMs, same template config, one grid).
// Per-GEMM: R6-verified deep-pipelined 256xBN kernel. Tile BM x 256,
// BM = MR*32. 8 waves (2M x 4N); per-wave (MR*16) x 64 = acc[MR][4]. BK=32.
// 4 LDS buffers, prefetch depth 3; steady vmcnt(2*LPT); tail cascade;
// one barrier per K-step; setprio around MFMA cluster.
// Block split: flat id h < nb0 -> GEMM 0, else GEMM 1. XCD remap (T1)
// applied PER HALF (both halves' nb % 8 == 0) for L2 locality + balance.
// LDS layout: byte(r,cb) = (r>>1)*128 + (r&1)*64 + (cb ^ (((r>>1)&3)<<4)),
// linear gload dest + inverse-permuted per-lane global source (rule 21).
// OUTMODE: 0=bf16, 1=f32(nt), 2=sigmoid f32(nt), 3=sigmoid f32(nt)+bf16 D
// BIASMODE: 0 none, 1 per-n, 2 per-m.  Requires NT = K/32 >= 3.
// ---------------------------------------------------------------------------
template <int OUTMODE, int BIASMODE, int MR>
__global__ __launch_bounds__(512, 2) void gemm8d(
    const short* __restrict__ A0, const short* __restrict__ B0,
    const float* __restrict__ bias0, void* __restrict__ C0,
    short* __restrict__ D0,
    int K0, int lda0, int ldb0, int ldc0,
    long long sA0, long long sB0, long long sC0,
    unsigned gx0, unsigned gy0, unsigned nb0,
    const short* __restrict__ A1, const short* __restrict__ B1,
    const float* __restrict__ bias1, void* __restrict__ C1,
    short* __restrict__ D1,
    int K1, int lda1, int ldb1, int ldc1,
    long long sA1, long long sB1, long long sC1,
    unsigned gx1, unsigned gy1,
    float scale) {
  constexpr int BM = MR * 32;
  constexpr int BN = 256;
  constexpr int LA = BM / 128;
  constexpr int LB = BN / 128;
  constexpr int LPT = LA + LB;
  constexpr int ABYTES = BM * 64;
  constexpr int BUFB = (BM + BN) * 64;
  constexpr int MH = MR / 2;
  __shared__ __align__(16) char smem[4 * BUFB];
  const int tid = threadIdx.x;
  const int lane = tid & 63, wid = tid >> 6;
  const int wm = wid >> 2, wn = wid & 3;

  // ---- select GEMM half ----
  const unsigned h = blockIdx.x;
  const bool sec = h >= nb0;
  const unsigned hh = sec ? h - nb0 : h;
  const unsigned nb = sec ? gridDim.x - nb0 : nb0;
  const unsigned gx = sec ? gx1 : gx0;
  const unsigned gy = sec ? gy1 : gy0;
  const short* Ap = sec ? A1 : A0;
  const short* Btp = sec ? B1 : B0;
  const float* bias = sec ? bias1 : bias0;
  void* Cptr = sec ? C1 : C0;
  short* C2p = sec ? D1 : D0;
  const int K = sec ? K1 : K0;
  const int lda = sec ? lda1 : lda0;
  const int ldb = sec ? ldb1 : ldb0;
  const int ldc = sec ? ldc1 : ldc0;
  const long long sA = sec ? sA1 : sA0;
  const long long sB = sec ? sB1 : sB0;
  const long long sC = sec ? sC1 : sC0;

  // ---- per-half XCD-aware bijective remap (T1) ----
  unsigned l = ((nb & 7u) == 0u) ? (hh & 7u) * (nb >> 3) + (hh >> 3) : hh;
  const unsigned bx = l % gx;
  const unsigned rem = l / gx;
  const unsigned by = rem % gy;
  const unsigned bz = rem / gy;

  const int zb = bz;
  const int m0 = by * BM, n0 = bx * BN;
  const char* Ab = (const char*)(Ap + (size_t)zb * sA);
  const char* Bb = (const char*)(Btp + (size_t)zb * sB);
  const size_t lda2 = (size_t)lda * 2, ldb2 = (size_t)ldb * 2;

  // Staging: dest d = j*8192 + tid*16 (linear). Inverse-map to (row, colbyte).
  int s_r[2], s_cb[2];
#pragma unroll
  for (int j = 0; j < 2; ++j) {
    const int d = j * 8192 + tid * 16;
    const int line = d >> 7;
    s_r[j] = line * 2 + ((d >> 6) & 1);
    s_cb[j] = (d & 63) ^ ((line & 3) << 4);
  }

  f32x4 acc[MR][4] = {};
  const int frow = lane & 15, fkg = lane >> 4;

  int ra[MR], rb[4];
#pragma unroll
  for (int mf = 0; mf < MR; ++mf) {
    const int R = wm * (MR * 16) + mf * 16 + frow;
    ra[mf] = (R >> 1) * 128 + (R & 1) * 64 + ((fkg * 16) ^ (((R >> 1) & 3) << 4));
  }
#pragma unroll
  for (int nf = 0; nf < 4; ++nf) {
    const int R = wn * 64 + nf * 16 + frow;
    rb[nf] = (R >> 1) * 128 + (R & 1) * 64 + ((fkg * 16) ^ (((R >> 1) & 3) << 4));
  }

  const int NT = K >> 5;

#define STAGE_A(t)                                                       \
  {                                                                      \
    char* base_ = smem + ((t) & 3) * BUFB;                               \
    const size_t kb_ = (size_t)(t) * 64;                                 \
    _Pragma("unroll")                                                    \
    for (int j = 0; j < LA; ++j)                                         \
      gload16(Ab + (size_t)(m0 + s_r[j]) * lda2 + kb_ + s_cb[j],         \
              base_ + j * 8192 + tid * 16);                              \
  }
#define STAGE_B(t)                                                       \
  {                                                                      \
    char* base_ = smem + ((t) & 3) * BUFB + ABYTES;                      \
    const size_t kb_ = (size_t)(t) * 64;                                 \
    _Pragma("unroll")                                                    \
    for (int j = 0; j < LB; ++j)                                         \
      gload16(Bb + (size_t)(n0 + s_r[j]) * ldb2 + kb_ + s_cb[j],         \
              base_ + j * 8192 + tid * 16);                              \
  }

  // prologue: 3 tiles in flight, wait for tile 0 (NT >= 3 at all call sites)
  STAGE_A(0); STAGE_B(0);
  STAGE_A(1); STAGE_B(1);
  STAGE_A(2); STAGE_B(2);
  waitcnt_vm<2 * LPT>();
  __builtin_amdgcn_sched_barrier(0);
  __builtin_amdgcn_s_barrier();
  __builtin_amdgcn_sched_barrier(0);

  for (int t = 0; t < NT; ++t) {
    const char* la = smem + (t & 3) * BUFB;
    const char* lb = la + ABYTES;
    FragU fa[MR], fb[4];
    // ---- phase 1: stage A(t+3) | read fa[0..MH), fb[0..4) | MFMA mf<MH ----
    if (t + 3 < NT) STAGE_A(t + 3);
#pragma unroll
    for (int mf = 0; mf < MH; ++mf) fa[mf].s = *(const s16x8*)(la + ra[mf]);
#pragma unroll
    for (int nf = 0; nf < 4; ++nf) fb[nf].s = *(const s16x8*)(lb + rb[nf]);
    __builtin_amdgcn_s_barrier();
    asm volatile("s_waitcnt lgkmcnt(0)" ::: "memory");
    __builtin_amdgcn_sched_barrier(0);
    __builtin_amdgcn_s_setprio(1);
#pragma unroll
    for (int mf = 0; mf < MH; ++mf)
#pragma unroll
      for (int nf = 0; nf < 4; ++nf)
        acc[mf][nf] = __builtin_amdgcn_mfma_f32_16x16x32_bf16(
            fa[mf].b, fb[nf].b, acc[mf][nf], 0, 0, 0);
    __builtin_amdgcn_s_setprio(0);
    __builtin_amdgcn_s_barrier();
    // ---- phase 2: stage B(t+3) | read fa[MH..MR) | MFMA mf>=MH ----
    if (t + 3 < NT) STAGE_B(t + 3);
#pragma unroll
    for (int mf = MH; mf < MR; ++mf) fa[mf].s = *(const s16x8*)(la + ra[mf]);
    __builtin_amdgcn_s_barrier();
    asm volatile("s_waitcnt lgkmcnt(0)" ::: "memory");
    __builtin_amdgcn_sched_barrier(0);
    __builtin_amdgcn_s_setprio(1);
#pragma unroll
    for (int mf = MH; mf < MR; ++mf)
#pragma unroll
      for (int nf = 0; nf < 4; ++nf)
        acc[mf][nf] = __builtin_amdgcn_mfma_f32_16x16x32_bf16(
            fa[mf].b, fb[nf].b, acc[mf][nf], 0, 0, 0);
    __builtin_amdgcn_s_setprio(0);
    // ---- end-of-iter wait (verified schedule) ----
    if (t + 3 < NT) {
      waitcnt_vm<2 * LPT>();
    } else if (t + 2 < NT) {
      waitcnt_vm<LPT>();
    } else if (t + 1 < NT) {
      waitcnt_vm<0>();
    } else {
      break;  // last iteration: no further LDS reads
    }
    __builtin_amdgcn_sched_barrier(0);
    __builtin_amdgcn_s_barrier();
    __builtin_amdgcn_sched_barrier(0);
  }
#undef STAGE_A
#undef STAGE_B

  const int rbase = (lane >> 4) * 4, cbase = lane & 15;
#pragma unroll
  for (int mf = 0; mf < MR; ++mf) {
#pragma unroll
    for (int nf = 0; nf < 4; ++nf) {
      const int gcol = n0 + wn * 64 + nf * 16 + cbase;
      float bn = (BIASMODE == 1) ? bias[gcol] : 0.f;
#pragma unroll
      for (int r = 0; r < 4; ++r) {
        const int grow = m0 + wm * (MR * 16) + mf * 16 + rbase + r;
        const size_t idx = (size_t)zb * sC + (size_t)grow * ldc + gcol;
        float v = acc[mf][nf][r];
        if constexpr (BIASMODE == 2) v += bias[grow]; else v += bn;
        if constexpr (OUTMODE == 0) {
          ((short*)Cptr)[idx] = f2bs(v);
        } else if constexpr (OUTMODE == 1) {
          __builtin_nontemporal_store(v, &((float*)Cptr)[idx]);
        } else if constexpr (OUTMODE == 2) {
          float p = 1.0f / (1.0f + __expf(-v * scale));
          __builtin_nontemporal_store(p, &((float*)Cptr)[idx]);
        } else {
          float p = 1.0f / (1.0f + __expf(-v * scale));
          __builtin_nontemporal_store(p, &((float*)Cptr)[idx]);
          C2p[idx] = f2bs(p);
        }
      }
    }
  }
}

// ---------------------------------------------------------------------------
// Fallback (tierB only): gload-staged 128x128 BK=64 GEMM, AF32 supported.
// ---------------------------------------------------------------------------
template <int OUTMODE, int BIASMODE, int AF32>
__global__ __launch_bounds__(256) void gemm_bt(
    const void* __restrict__ Aptr, const short* __restrict__ Btp,
    const float* __restrict__ bias, void* __restrict__ Cptr,
    short* __restrict__ C2p,
    int K, int lda, int ldb, int ldc,
    long long sA, long long sB, long long sC, float scale) {
  __shared__ __align__(16) short lsA[128 * 64];
  __shared__ __align__(16) short lsB[128 * 64];
  const int tid = threadIdx.x;
  const int lane = tid & 63, wid = tid >> 6;
  const int zb = blockIdx.z;
  const int m0 = blockIdx.y * 128, n0 = blockIdx.x * 128;
  const short* Ab = AF32 ? nullptr : (const short*)Aptr + (size_t)zb * sA;
  const float* Af = AF32 ? (const float*)Aptr + (size_t)zb * sA : nullptr;
  const short* Bt = Btp + (size_t)zb * sB;

  f32x4 acc[4][4] = {};
  const int woffM = (wid >> 1) * 64, woffN = (wid & 1) * 64;
  const int frow = lane & 15, fkg = lane >> 4;

  for (int k0 = 0; k0 < K; k0 += 64) {
    if (k0) __syncthreads();
    if constexpr (!AF32) {
#pragma unroll
      for (int i = 0; i < 4; ++i) {
        const int f = i * 4096 + tid * 16;
        const int row = f >> 7, colb = f & 127;
        gload16((const char*)Ab + ((size_t)(m0 + row) * lda + k0) * 2 + colb,
                (char*)lsA + f);
      }
    } else {
#pragma unroll
      for (int i = 0; i < 8; ++i) {
        int f = tid + i * 256;
        int row = f >> 4, c4 = f & 15;
        f32x4 v = *(const f32x4*)&Af[(size_t)(m0 + row) * lda + k0 + c4 * 4];
        union { short s[4]; unsigned long long q; } cv;
#pragma unroll
        for (int j = 0; j < 4; ++j) cv.s[j] = f2bs(v[j]);
        *(unsigned long long*)&lsA[row * 64 + c4 * 4] = cv.q;
      }
    }
#pragma unroll
    for (int i = 0; i < 4; ++i) {
      const int f = i * 4096 + tid * 16;
      const int row = f >> 7, colb = f & 127;
      gload16((const char*)Bt + ((size_t)(n0 + row) * ldb + k0) * 2 + colb,
              (char*)lsB + f);
    }
    __syncthreads();
#pragma unroll
    for (int kk = 0; kk < 2; ++kk) {
      const int kb = kk * 32 + fkg * 8;
      FragU fa[4], fb[4];
#pragma unroll
      for (int mf = 0; mf < 4; ++mf)
        fa[mf].s = *(const s16x8*)&lsA[(woffM + mf * 16 + frow) * 64 + kb];
#pragma unroll
      for (int nf = 0; nf < 4; ++nf)
        fb[nf].s = *(const s16x8*)&lsB[(woffN + nf * 16 + frow) * 64 + kb];
#pragma unroll
      for (int mf = 0; mf < 4; ++mf)
#pragma unroll
        for (int nf = 0; nf < 4; ++nf)
          acc[mf][nf] = __builtin_amdgcn_mfma_f32_16x16x32_bf16(
              fa[mf].b, fb[nf].b, acc[mf][nf], 0, 0, 0);
    }
  }

  const int rbase = (lane >> 4) * 4, cbase = lane & 15;
#pragma unroll
  for (int mf = 0; mf < 4; ++mf) {
#pragma unroll
    for (int nf = 0; nf < 4; ++nf) {
      const int gcol = n0 + woffN + nf * 16 + cbase;
      float bn = (BIASMODE == 1) ? bias[gcol] : 0.f;
#pragma unroll
      for (int r = 0; r < 4; ++r) {
        const int grow = m0 + woffM + mf * 16 + rbase + r;
        const size_t idx = (size_t)zb * sC + (size_t)grow * ldc + gcol;
        float v = acc[mf][nf][r];
        if constexpr (BIASMODE == 2) v += bias[grow]; else v += bn;
        if constexpr (OUTMODE == 0) {
          ((short*)Cptr)[idx] = f2bs(v);
        } else if constexpr (OUTMODE == 1) {
          ((float*)Cptr)[idx] = v;
        } else if constexpr (OUTMODE == 2) {
          ((float*)Cptr)[idx] = 1.0f / (1.0f + __expf(-v * scale));
        } else {
          float p = 1.0f / (1.0f + __expf(-v * scale));
          ((float*)Cptr)[idx] = p;
          C2p[idx] = f2bs(p);
        }
      }
    }
  }
}

extern "C" void kernel_launch(void* const* d_in, const int* in_sizes, int n_in,
                              void* d_out, int out_size, void* d_ws, size_t ws_size,
                              hipStream_t stream) {
  const float* in1 = (const float*)d_in[0];   // [16][512][2048]
  const float* in2 = (const float*)d_in[1];   // [16][768][1024]
  const float* Wq1 = (const float*)d_in[2];  const float* bq1 = (const float*)d_in[3];
  const float* Wk1 = (const float*)d_in[4];  const float* bk1 = (const float*)d_in[5];
  const float* Wv1 = (const float*)d_in[6];  const float* bv1 = (const float*)d_in[7];
  const float* Wq2 = (const float*)d_in[8];  const float* bq2 = (const float*)d_in[9];
  const float* Wk2 = (const float*)d_in[10]; const float* bk2 = (const float*)d_in[11];
  const float* Wv2 = (const float*)d_in[12]; const float* bv2 = (const float*)d_in[13];

  float* out = (float*)d_out;
  float* ctx2   = out;                                      // [16][2048][512]
  float* probs2 = out + (size_t)16 * 2048 * 512;            // [16][2048][1024]
  float* ctx1   = probs2 + (size_t)16 * 2048 * 1024;        // [16][1024][512]
  float* probs1 = ctx1 + (size_t)16 * 1024 * 512;           // [16][1024][2048]

  char* ws = (char*)d_ws;
  constexpr size_t O_WQ1T = 0;
  constexpr size_t O_WK1T = O_WQ1T + (size_t)512 * 512 * 2;
  constexpr size_t O_WV1T = O_WK1T + (size_t)512 * 512 * 2;
  constexpr size_t O_WQ2T = O_WV1T + (size_t)512 * 512 * 2;
  constexpr size_t O_WK2T = O_WQ2T + (size_t)768 * 512 * 2;
  constexpr size_t O_WV2T = O_WK2T + (size_t)768 * 512 * 2;
  constexpr size_t O_B1   = O_WV2T + (size_t)768 * 512 * 2;
  constexpr size_t O_B2   = O_B1 + 4096;
  constexpr size_t O_QK1  = O_B2 + 4096;                          // [32768][1024]
  constexpr size_t O_V1T  = O_QK1 + (size_t)32768 * 1024 * 2;     // [16][512][2048]
  constexpr size_t O_QK2  = O_V1T + (size_t)16 * 512 * 2048 * 2;  // [16384][1024]
  constexpr size_t O_V2T  = O_QK2 + (size_t)16384 * 1024 * 2;     // [16][512][1024]
  constexpr size_t O_X1B  = O_V2T + (size_t)16 * 512 * 1024 * 2;  // [32768][512]
  constexpr size_t O_X2B  = O_X1B + (size_t)32768 * 512 * 2;      // [16384][768]
  constexpr size_t O_PB1  = O_X2B + (size_t)16384 * 768 * 2;      // bf16 probs1
  constexpr size_t O_PB2  = O_PB1 + (size_t)16 * 1024 * 2048 * 2; // bf16 probs2
  constexpr size_t NEED_A = O_PB2 + (size_t)16 * 2048 * 1024 * 2;
  constexpr size_t NEED_B = O_PB1;

  short* wq1t = (short*)(ws + O_WQ1T);
  short* wk1t = (short*)(ws + O_WK1T);
  short* wv1t = (short*)(ws + O_WV1T);
  short* wq2t = (short*)(ws + O_WQ2T);
  short* wk2t = (short*)(ws + O_WK2T);
  short* wv2t = (short*)(ws + O_WV2T);
  float* b1c  = (float*)(ws + O_B1);
  float* b2c  = (float*)(ws + O_B2);
  short* qk1  = (short*)(ws + O_QK1);
  short* v1t  = (short*)(ws + O_V1T);
  short* qk2  = (short*)(ws + O_QK2);
  short* v2t  = (short*)(ws + O_V2T);
  short* x1b  = (short*)(ws + O_X1B);
  short* x2b  = (short*)(ws + O_X2B);
  short* pb1  = (short*)(ws + O_PB1);
  short* pb2  = (short*)(ws + O_PB2);

  const bool tierA = ws_size >= NEED_A;
  const bool tierB = ws_size >= NEED_B;
  if (!tierB) { x1b = (short*)probs1; x2b = (short*)probs2; }

  dim3 blk256(256), blk512(512);
  dim3 blkT(32, 8);

  // ---- stage 0 ----
  transpose_cvt<<<dim3(64, 8, 16), blkT, 0, stream>>>(in1, x1b, 512, 2048);
  transpose_cvt<<<dim3(32, 12, 16), blkT, 0, stream>>>(in2, x2b, 768, 1024);
  prep_weights<<<dim3(16, 12, 7), blkT, 0, stream>>>(
      Wq1, Wk1, Wv1, Wq2, Wk2, Wv2, wq1t, wk1t, wv1t, wq2t, wk2t, wv2t,
      bq1, bk1, bq2, bk2, b1c, b2c);

  const float scale = 0.04419417382415922f;  // 1/sqrt(512)
  const short* q1p = qk1;        // lda 1024
  const short* k1p = qk1 + 512;
  const short* q2p = qk2;
  const short* k2p = qk2 + 512;

  if (tierA) {
    // ---- P1: qk1 + qk2 (one launch, 512+256 = 768 blocks) ----
    gemm8d<0, 1, 8><<<dim3(768), blk512, 0, stream>>>(
        x1b, wq1t, b1c, qk1, nullptr, 512, 512, 512, 1024, 0, 0, 0,
        4u, 128u, 512u,
        x2b, wq2t, b2c, qk2, nullptr, 768, 768, 768, 1024, 0, 0, 0,
        4u, 64u, 1.f);
    // ---- P2: v1t + v2t (MR=4; 512+256 = 768 blocks) ----
    gemm8d<0, 2, 4><<<dim3(768), blk512, 0, stream>>>(
        wv1t, x1b, bv1, v1t, nullptr, 512, 512, 512, 2048,
        0, (long long)2048 * 512, (long long)512 * 2048,
        8u, 4u, 512u,
        wv2t, x2b, bv2, v2t, nullptr, 768, 768, 768, 1024,
        0, (long long)1024 * 768, (long long)512 * 1024,
        4u, 4u, 1.f);
    // ---- P3: scores1 + scores2 (512+512 = 1024 blocks) ----
    gemm8d<3, 0, 8><<<dim3(1024), blk512, 0, stream>>>(
        q2p, k1p, nullptr, probs1, pb1, 512, 1024, 1024, 2048,
        (long long)1024 * 1024, (long long)2048 * 1024, (long long)1024 * 2048,
        8u, 4u, 512u,
        q1p, k2p, nullptr, probs2, pb2, 512, 1024, 1024, 1024,
        (long long)2048 * 1024, (long long)1024 * 1024, (long long)2048 * 1024,
        4u, 8u, scale);
    // ---- P4: ctx1 + ctx2 (MR=4; 256+512 = 768 blocks) ----
    gemm8d<1, 0, 4><<<dim3(768), blk512, 0, stream>>>(
        pb1, v1t, nullptr, ctx1, nullptr, 2048, 2048, 2048, 512,
        (long long)1024 * 2048, (long long)512 * 2048, (long long)1024 * 512,
        2u, 8u, 256u,
        pb2, v2t, nullptr, ctx2, nullptr, 1024, 1024, 1024, 512,
        (long long)2048 * 1024, (long long)512 * 1024, (long long)2048 * 512,
        2u, 16u, 1.f);
  } else {
    gemm_bt<0, 1, 0><<<dim3(8, 256, 1), blk256, 0, stream>>>(
        x1b, wq1t, b1c, qk1, nullptr, 512, 512, 512, 1024, 0, 0, 0, 1.f);
    gemm_bt<0, 1, 0><<<dim3(8, 128, 1), blk256, 0, stream>>>(
        x2b, wq2t, b2c, qk2, nullptr, 768, 768, 768, 1024, 0, 0, 0, 1.f);
    gemm_bt<0, 2, 0><<<dim3(16, 4, 16), blk256, 0, stream>>>(
        wv1t, x1b, bv1, v1t, nullptr, 512, 512, 512, 2048,
        0, (long long)2048 * 512, (long long)512 * 2048, 1.f);
    gemm_bt<0, 2, 0><<<dim3(8, 4, 16), blk256, 0, stream>>>(
        wv2t, x2b, bv2, v2t, nullptr, 768, 768, 768, 1024,
        0, (long long)1024 * 768, (long long)512 * 1024, 1.f);
    gemm_bt<2, 0, 0><<<dim3(16, 8, 16), blk256, 0, stream>>>(
        q2p, k1p, nullptr, probs1, nullptr, 512, 1024, 1024, 2048,
        (long long)1024 * 1024, (long long)2048 * 1024, (long long)1024 * 2048, scale);
    gemm_bt<2, 0, 0><<<dim3(8, 16, 16), blk256, 0, stream>>>(
        q1p, k2p, nullptr, probs2, nullptr, 512, 1024, 1024, 1024,
        (long long)2048 * 1024, (long long)1024 * 1024, (long long)2048 * 1024, scale);
    gemm_bt<1, 0, 1><<<dim3(4, 8, 16), blk256, 0, stream>>>(
        probs1, v1t, nullptr, ctx1, nullptr, 2048, 2048, 2048, 512,
        (long long)1024 * 2048, (long long)512 * 2048, (long long)1024 * 512, 1.f);
    gemm_bt<1, 0, 1><<<dim3(4, 16, 16), blk256, 0, stream>>>(
        probs2, v2t, nullptr, ctx2, nullptr, 1024, 1024, 1024, 512,
        (long long)2048 * 1024, (long long)512 * 1024, (long long)2048 * 512, 1.f);
  }
}